// Round 12
// baseline (78.322 us; speedup 1.0000x reference)
//
#include <hip/hip_runtime.h>
#include <hip/hip_bf16.h>

#define NPIX 8192
#define BATCH 8
#define CCH 128
#define CEMB 64
#define NR 13            // doubling rounds: covers ancestor distance < 8192
#define LCAP 2048        // entry-list / touched-list capacity per batch
#define STHR 69.0f       // s <= 69 <=> w = exp(-s) >= ~1e-30

typedef short bf16x8 __attribute__((ext_vector_type(8)));
typedef float f32x4 __attribute__((ext_vector_type(4)));

__device__ __forceinline__ unsigned short f2b(float f) {   // f32 -> bf16 RNE
    unsigned int u = __float_as_uint(f);
    u = (u + 0x7FFFu + ((u >> 16) & 1u)) >> 16;
    return (unsigned short)u;
}
__device__ __forceinline__ unsigned int cvtpk(float lo, float hi) {
    unsigned int r;
    asm("v_cvt_pk_bf16_f32 %0, %1, %2" : "=v"(r) : "v"(lo), "v"(hi));
    return r;
}

// ---------------------------------------------------------------------------
// Fused embed + edge-energy via MFMA, split by edge direction (blockIdx.z):
//   z=0: s_right[p] = || W_embed (x[p+1]-x[p]) ||^2
//   z=1: s_down [p] = || W_embed (x[p+128]-x[p]) ||^2
// 32KB LDS/block (Wh 16K + B 16K) -> 5 blocks/CU. Junk values at invalid
// edges (row end / last row) are never read by k_prep (tree edges are real
// grid edges only).
// ---------------------------------------------------------------------------
#define EP 64
__global__ void __launch_bounds__(256) k_embedw(
    const float* __restrict__ last_fm,
    const float* __restrict__ W_embed,
    float* __restrict__ sR,     // [B][NPIX]
    float* __restrict__ sD)     // [B][NPIX]
{
    __shared__ __align__(16) unsigned short Wh[CEMB * CCH];    // 16KB
    __shared__ __align__(16) unsigned short BB[16 * EP * 8];   // 16KB
    const int tid = threadIdx.x;
    const int b = blockIdx.y;
    const int pbase = blockIdx.x * EP;
    const int z = blockIdx.z;

    for (int i = tid; i < CEMB * CCH; i += 256) {
        const int ce = i >> 7, c = i & 127;
        Wh[ce * 128 + (((c >> 3) ^ (ce & 15)) << 3) + (c & 7)] = f2b(W_embed[i]);
    }
    {
        const int chunk = tid >> 4, p4 = tid & 15;
        const int gp4 = pbase + p4 * 4;
        float dv[8][4];
        if (z == 0) {
            const bool hr = gp4 + 4 < NPIX;
#pragma unroll
            for (int j = 0; j < 8; ++j) {
                const float* src = last_fm + ((size_t)(b * CCH + chunk * 8 + j)) * NPIX;
                const float4 a = *(const float4*)&src[gp4];
                const float xn = hr ? src[gp4 + 4] : a.w;
                dv[j][0] = a.y - a.x; dv[j][1] = a.z - a.y;
                dv[j][2] = a.w - a.z; dv[j][3] = xn - a.w;
            }
        } else {
            const bool hd = gp4 + 131 < NPIX;
#pragma unroll
            for (int j = 0; j < 8; ++j) {
                const float* src = last_fm + ((size_t)(b * CCH + chunk * 8 + j)) * NPIX;
                const float4 a = *(const float4*)&src[gp4];
                const float4 g = hd ? *(const float4*)&src[gp4 + 128] : a;
                dv[j][0] = g.x - a.x; dv[j][1] = g.y - a.y;
                dv[j][2] = g.z - a.z; dv[j][3] = g.w - a.w;
            }
        }
#pragma unroll
        for (int q = 0; q < 4; ++q) {
            const int p = p4 * 4 + q;
            const int row = p * 16 + (chunk ^ (p & 15));
            uint4 u;
            u.x = cvtpk(dv[0][q], dv[1][q]); u.y = cvtpk(dv[2][q], dv[3][q]);
            u.z = cvtpk(dv[4][q], dv[5][q]); u.w = cvtpk(dv[6][q], dv[7][q]);
            *(uint4*)&BB[row * 8] = u;
        }
    }
    __syncthreads();

    const int lane = tid & 63, wv = tid >> 6;
    f32x4 ac[4];
#pragma unroll
    for (int i = 0; i < 4; ++i) ac[i] = (f32x4){0.f, 0.f, 0.f, 0.f};
    const int pl = wv * 16 + (lane & 15);
#pragma unroll
    for (int ks = 0; ks < 4; ++ks) {
        const int chunk = ks * 4 + (lane >> 4);
        const int row = pl * 16 + (chunk ^ (pl & 15));
        const bf16x8 bx = *(const bf16x8*)&BB[row * 8];
#pragma unroll
        for (int ot = 0; ot < 4; ++ot) {
            const int ce = ot * 16 + (lane & 15);
            const bf16x8 aw = *(const bf16x8*)&Wh[ce * 128 + ((chunk ^ (ce & 15)) << 3)];
            ac[ot] = __builtin_amdgcn_mfma_f32_16x16x32_bf16(aw, bx, ac[ot], 0, 0, 0);
        }
    }
    float pr = 0.f;
#pragma unroll
    for (int ot = 0; ot < 4; ++ot)
#pragma unroll
        for (int r = 0; r < 4; ++r) pr += ac[ot][r] * ac[ot][r];
    pr += __shfl_xor(pr, 16); pr += __shfl_xor(pr, 32);
    if (lane < 16) {
        const int p = pbase + wv * 16 + lane;
        (z ? sD : sR)[(size_t)b * NPIX + p] = pr;
    }
}

// ---------------------------------------------------------------------------
// Wave-level exclusive scan over a 1024-thread block (3 barriers, not 10).
// ---------------------------------------------------------------------------
__device__ __forceinline__ unsigned int wave_scan_offset(
    unsigned int c, unsigned int* wtot, int tid, unsigned int* total)
{
    __syncthreads();                         // protect wtot reuse
    unsigned int x = c;
#pragma unroll
    for (int off = 1; off < 64; off <<= 1) {
        const unsigned int y = __shfl_up(x, off);
        if ((tid & 63) >= off) x += y;
    }
    if ((tid & 63) == 63) wtot[tid >> 6] = x;
    __syncthreads();
    if (tid < 16) {
        unsigned int t = wtot[tid];
#pragma unroll
        for (int off = 1; off < 16; off <<= 1) {
            const unsigned int y = __shfl_up(t, off);
            if (tid >= off) t += y;
        }
        wtot[tid] = t;
    }
    __syncthreads();
    const unsigned int waveOff = (tid >> 6) ? wtot[(tid >> 6) - 1] : 0u;
    *total = wtot[15];
    return waveOff + x - c;
}

// ---------------------------------------------------------------------------
// Prep (per batch, 1024 thr): w from s-arrays (edge identified by pixel-index
// delta +-1/+-128), thresholded -> compact doubling-entry lists, touched list,
// per-touched (1-w^2), 1/norm, per-pixel dense scale, per-pixel fixidx.
// Also (b==0) converts W_refine to the swizzled bf16 image for k_refine.
// ---------------------------------------------------------------------------
__global__ void __launch_bounds__(1024) k_prep(
    const int* __restrict__ bfs_order,
    const int* __restrict__ bfs_parent,
    const float* __restrict__ sR,
    const float* __restrict__ sD,
    const float* __restrict__ W_refine,
    unsigned short* __restrict__ Wrg,    // [CCH*CCH] swizzled bf16
    unsigned int* __restrict__ listKK,   // [B][LCAP]
    float* __restrict__ listW,           // [B][LCAP]
    int* __restrict__ loffg,             // [B][NR+1]
    unsigned int* __restrict__ tKPg,     // [B][LCAP]
    float* __restrict__ tOMWg,           // [B][LCAP]
    float* __restrict__ tRNg,            // [B][LCAP]
    int* __restrict__ tcntg,             // [B]
    float* __restrict__ scaleg,          // [B][NPIX] pixel order
    short* __restrict__ fixidx)          // [B][NPIX] pixel order, -1 default
{
    __shared__ unsigned short anc[NPIX];            // 16KB (in-place doubled)
    __shared__ float Wc[NPIX];                      // 32KB (doubled; later normA)
    __shared__ float w0[NPIX];                      // 32KB persistent weights
    __shared__ unsigned short ordL[NPIX];           // 16KB bfs k -> pixel
    __shared__ unsigned short mk[NPIX];             // 16KB touched marks
    __shared__ unsigned int wtot[16];               // scan scratch
    __shared__ unsigned int eKK[LCAP];              // 8KB entry cache
    __shared__ float eW[LCAP];                      // 8KB
    __shared__ unsigned int tKPc[LCAP];             // 8KB touched cache
    __shared__ int loffL[NR + 1];
    __shared__ int sTot;

    const int b = blockIdx.x, tid = threadIdx.x;
    const int* par = bfs_parent + (size_t)b * NPIX;
    const int* ord = bfs_order + (size_t)b * NPIX;
    const size_t base = (size_t)b * NPIX;

    if (b == 0) {   // one-time W_refine -> swizzled bf16 (consumed by k_refine)
        for (int i = tid; i < CCH * CCH; i += 1024) {
            const int o = i >> 7, c = i & 127;
            Wrg[o * 128 + (((c >> 3) ^ (o & 15)) << 3) + (c & 7)] = f2b(W_refine[i]);
        }
    }
    for (int k = tid; k < NPIX; k += 1024) {
        anc[k] = k ? (unsigned short)par[k] : 0;     // root self-loop
        ordL[k] = (unsigned short)ord[k];
        mk[k] = 0;
        scaleg[base + k] = 1.0f;                     // default dense scale
        fixidx[base + k] = -1;
    }
    if (tid == 0) loffL[0] = 0;
    __syncthreads();
    for (int k = tid; k < NPIX; k += 1024) {
        float w = 0.f;
        if (k) {
            const int u = ordL[k], v = ordL[anc[k]];
            const int d = u - v;
            float s;
            if (d == 1)        s = sR[base + v];
            else if (d == -1)  s = sR[base + u];
            else if (d == 128) s = sD[base + v];
            else               s = sD[base + u];
            w = (s <= STHR) ? __expf(-s) : 0.f;
        }
        Wc[k] = w; w0[k] = w;
    }
    __syncthreads();

    // ---- doubling rounds with compaction (early exit when a round is empty) ----
    int r = 0;
    for (; r < NR; ++r) {
        const int k0 = tid * 8;
        float wv8[8]; unsigned short av[8]; unsigned int c = 0;
#pragma unroll
        for (int j = 0; j < 8; ++j) { wv8[j] = Wc[k0 + j]; av[j] = anc[k0 + j]; c += (wv8[j] != 0.f); }
        unsigned int total;
        const unsigned int off0 = wave_scan_offset(c, wtot, tid, &total);
        int wpos = loffL[r] + (int)off0;
#pragma unroll
        for (int j = 0; j < 8; ++j) {
            if (wv8[j] != 0.f) {
                if (wpos < LCAP) {
                    const unsigned int kk = (unsigned)(k0 + j) | ((unsigned)av[j] << 16);
                    listKK[(size_t)b * LCAP + wpos] = kk;
                    listW[(size_t)b * LCAP + wpos] = wv8[j];
                    eKK[wpos] = kk; eW[wpos] = wv8[j];
                    mk[k0 + j] = 1; mk[av[j]] = 1;
                }
                ++wpos;
            }
        }
        __syncthreads();
        const int tot = min((int)total, LCAP - loffL[r]);
        if (tid == 0) loffL[r + 1] = loffL[r] + tot;
        __syncthreads();
        if (tot == 0) { ++r; break; }
        if (r + 1 < NR) {  // in-place doubling: read-phase -> barrier -> write-phase
            unsigned short a2[8]; float w2[8];
#pragma unroll
            for (int j = 0; j < 8; ++j) { const int a = av[j]; w2[j] = wv8[j] * Wc[a]; a2[j] = anc[a]; }
            __syncthreads();
#pragma unroll
            for (int j = 0; j < 8; ++j) { Wc[k0 + j] = w2[j]; anc[k0 + j] = a2[j]; }
            __syncthreads();
        }
    }
    if (tid == 0) for (int rr = r; rr < NR; ++rr) loffL[rr + 1] = loffL[r];
    __syncthreads();
    if (tid <= NR) loffg[b * (NR + 1) + tid] = loffL[tid];

    // ---- touched compaction (sorted by k) ----
    {
        const int k0 = tid * 8;
        unsigned short fl[8]; unsigned int c = 0;
#pragma unroll
        for (int j = 0; j < 8; ++j) { fl[j] = mk[k0 + j]; c += fl[j]; }
        unsigned int total;
        const unsigned int off0 = wave_scan_offset(c, wtot, tid, &total);
        int wpos = (int)off0;
#pragma unroll
        for (int j = 0; j < 8; ++j) {
            if (fl[j]) {
                if (wpos < LCAP) {
                    const unsigned int tp = (unsigned)(k0 + j) | ((unsigned)ordL[k0 + j] << 16);
                    tKPg[(size_t)b * LCAP + wpos] = tp; tKPc[wpos] = tp;
                }
                ++wpos;
            }
        }
        if (tid == 0) { sTot = min((int)total, LCAP); tcntg[b] = min((int)total, LCAP); }
        __syncthreads();
    }

    // ---- norm channel sparse simulation (ones vector) ----
    float* normA = Wc;                               // Wc dead, reuse as f32 array
    for (int k = tid; k < NPIX; k += 1024) normA[k] = 1.0f;
    __syncthreads();
    for (int rr = 0; rr < NR; ++rr) {                // UP (ascending chunks)
        const int e0 = loffL[rr], e1 = loffL[rr + 1];
        for (int bb = e0; bb < e1; bb += 1024) {
            const int e = bb + tid; const bool ok = e < e1;
            const unsigned int kk = ok ? eKK[e] : 0u;
            const float W = ok ? eW[e] : 0.f;
            const float a = normA[kk & 0xFFFFu];
            __syncthreads();
            if (W != 0.f) atomicAdd(&normA[kk >> 16], W * a);
            __syncthreads();
        }
    }
    for (int k = tid; k < NPIX; k += 1024) {         // alpha = (1-w^2) * A
        const float w = w0[k];
        normA[k] *= (1.f - w * w);
    }
    __syncthreads();
    for (int rr = 0; rr < NR; ++rr) {                // DOWN (descending chunks)
        const int e0 = loffL[rr], e1 = loffL[rr + 1];
        if (e1 <= e0) continue;
        const int cst = e0 + ((e1 - 1 - e0) / 1024) * 1024;
        for (int bb = cst; bb >= e0; bb -= 1024) {
            const int e = bb + tid; const bool ok = e < e1;
            const unsigned int kk = ok ? eKK[e] : 0u;
            const float W = ok ? eW[e] : 0.f;
            const float va = normA[kk >> 16];
            const float vs = normA[kk & 0xFFFFu];
            __syncthreads();
            if (ok) normA[kk & 0xFFFFu] = fmaf(W, va, vs);
            __syncthreads();
        }
    }
    // ---- per-touched outputs + scale/fixidx overwrite ----
    const int tc = sTot;
    for (int i = tid; i < tc; i += 1024) {
        const unsigned int tp = tKPc[i];
        const int k = (int)(tp & 0xFFFFu), pix = (int)(tp >> 16);
        const float w = w0[k];
        const float omw2 = 1.f - w * w;
        const float rn = 1.f / normA[k];
        tOMWg[(size_t)b * LCAP + i] = omw2;
        tRNg[(size_t)b * LCAP + i] = rn;
        scaleg[base + pix] = omw2 * rn;
        fixidx[base + pix] = (short)i;
    }
}

// ---------------------------------------------------------------------------
// Sparse corrections: per (batch, channel) wave, exact doubling sweeps on
// touched nodes in LDS; emits filt[c] = Y*rn per touched pixel.
// ---------------------------------------------------------------------------
__global__ void __launch_bounds__(256) k_sparse(
    const float* __restrict__ last_fm,
    const unsigned int* __restrict__ listKK,
    const float* __restrict__ listW,
    const int* __restrict__ loffg,
    const unsigned int* __restrict__ tKPg,
    const float* __restrict__ tOMWg,
    const float* __restrict__ tRNg,
    const int* __restrict__ tcntg,
    float* __restrict__ dltg)           // [B][LCAP][CCH] filt values
{
    __shared__ float As[4][NPIX];            // 128KB
    const int lane = threadIdx.x & 63;
    const int wv = threadIdx.x >> 6;
    const int b = blockIdx.x >> 5;
    const int c = (blockIdx.x & 31) * 4 + wv;
    float* A = As[wv];
    const int tc = tcntg[b];
    const unsigned int* tkp = tKPg + (size_t)b * LCAP;
    const float* tom = tOMWg + (size_t)b * LCAP;
    const float* trn = tRNg + (size_t)b * LCAP;
    const unsigned int* lkk = listKK + (size_t)b * LCAP;
    const float* lw = listW + (size_t)b * LCAP;
    const float* src = last_fm + ((size_t)(b * CCH + c)) * NPIX;
    int lo[NR + 1];
#pragma unroll
    for (int i = 0; i <= NR; ++i) lo[i] = loffg[b * (NR + 1) + i];

    for (int i = lane; i < tc; i += 64) {
        const unsigned int tp = tkp[i];
        A[tp & 0xFFFFu] = src[tp >> 16];
    }
    for (int r = 0; r < NR; ++r) {
        for (int e0 = lo[r]; e0 < lo[r + 1]; e0 += 64) {
            const int e = e0 + lane; const bool ok = e < lo[r + 1];
            const unsigned int kk = ok ? lkk[e] : 0u;
            const float W = ok ? lw[e] : 0.f;
            const float a = A[kk & 0xFFFFu];
            if (ok && W != 0.f) atomicAdd(&A[kk >> 16], W * a);
        }
    }
    for (int i = lane; i < tc; i += 64) A[tkp[i] & 0xFFFFu] *= tom[i];
    for (int r = 0; r < NR; ++r) {
        const int e0 = lo[r], e1 = lo[r + 1];
        if (e1 <= e0) continue;
        const int cst = e0 + ((e1 - 1 - e0) / 64) * 64;
        for (int bb = cst; bb >= e0; bb -= 64) {
            const int e = bb + lane; const bool ok = e < e1;
            const unsigned int kk = ok ? lkk[e] : 0u;
            const float W = ok ? lw[e] : 0.f;
            const float va = A[kk >> 16];
            const float vs = A[kk & 0xFFFFu];
            if (ok) A[kk & 0xFFFFu] = fmaf(W, va, vs);
        }
    }
    for (int i = lane; i < tc; i += 64) {
        const unsigned int tp = tkp[i];
        const int k = (int)(tp & 0xFFFFu);
        dltg[((size_t)b * LCAP + i) * CCH + c] = A[k] * trn[i];
    }
}

// ---------------------------------------------------------------------------
// Refine via MFMA, operand-swapped (D[p][o]) and split by o-halves
// (blockIdx.z): Wr-half 16KB + XB 16KB = 32KB LDS -> 5 blocks/CU.
// X = latent + scale*last_fm (untouched) or latent + filt (touched, exact).
// ---------------------------------------------------------------------------
#define RP 64
__global__ void __launch_bounds__(256) k_refine(
    const float* __restrict__ last_fm,
    const float* __restrict__ latent,
    const float* __restrict__ scaleg,
    const short* __restrict__ fixidx,
    const float* __restrict__ dltg,
    const unsigned short* __restrict__ Wrg,
    float* __restrict__ out)
{
    __shared__ __align__(16) unsigned short Wr[64 * CCH];      // 16KB (o-half)
    __shared__ __align__(16) unsigned short XB[16 * RP * 8];   // 16KB
    const int tid = threadIdx.x;
    const int b = blockIdx.y;
    const int pbase = blockIdx.x * RP;
    const int half = blockIdx.z;

    for (int i = tid; i < 64 * CCH / 8; i += 256)
        ((uint4*)Wr)[i] = ((const uint4*)Wrg)[half * (64 * CCH / 8) + i];
    {
        const int chunk = tid >> 4, p4 = tid & 15;
        const int gp4 = pbase + p4 * 4;
        const float4 sc4 = *(const float4*)&scaleg[(size_t)b * NPIX + gp4];
        const short4 fi4 = *(const short4*)&fixidx[(size_t)b * NPIX + gp4];
        float4 l[8], x[8];
#pragma unroll
        for (int j = 0; j < 8; ++j) {
            const size_t rb = ((size_t)(b * CCH + chunk * 8 + j)) * NPIX + gp4;
            l[j] = *(const float4*)&latent[rb];
            x[j] = *(const float4*)&last_fm[rb];
        }
        const short fiq[4] = {fi4.x, fi4.y, fi4.z, fi4.w};
#pragma unroll
        for (int q = 0; q < 4; ++q) {
            const int p = p4 * 4 + q;
            const int row = p * 16 + (chunk ^ (p & 15));
            float v[8];
            if (fiq[q] >= 0) {
#pragma unroll
                for (int j = 0; j < 8; ++j)
                    v[j] = (&l[j].x)[q]
                         + dltg[((size_t)b * LCAP + fiq[q]) * CCH + chunk * 8 + j];
            } else {
#pragma unroll
                for (int j = 0; j < 8; ++j)
                    v[j] = fmaf((&sc4.x)[q], (&x[j].x)[q], (&l[j].x)[q]);
            }
            uint4 u;
            u.x = cvtpk(v[0], v[1]); u.y = cvtpk(v[2], v[3]);
            u.z = cvtpk(v[4], v[5]); u.w = cvtpk(v[6], v[7]);
            *(uint4*)&XB[row * 8] = u;
        }
    }
    __syncthreads();

    const int lane = tid & 63, wv = tid >> 6;
    f32x4 acc[4];                        // [pt], 16 local o's per wave
#pragma unroll
    for (int i = 0; i < 4; ++i) acc[i] = (f32x4){0.f, 0.f, 0.f, 0.f};
    const int oL = wv * 16 + (lane & 15);          // local o row (0..63)
#pragma unroll
    for (int ks = 0; ks < 4; ++ks) {
        const int chunk = ks * 4 + (lane >> 4);
        const bf16x8 bw = *(const bf16x8*)&Wr[oL * 128 + ((chunk ^ (oL & 15)) << 3)];
#pragma unroll
        for (int pt = 0; pt < 4; ++pt) {
            const int p = pt * 16 + (lane & 15);
            const int row = p * 16 + (chunk ^ (p & 15));
            const bf16x8 ax = *(const bf16x8*)&XB[row * 8];
            acc[pt] = __builtin_amdgcn_mfma_f32_16x16x32_bf16(ax, bw, acc[pt], 0, 0, 0);
        }
    }
    const int o = half * 64 + oL;
    float* orow = &out[((size_t)(b * CCH + o)) * NPIX + pbase];
#pragma unroll
    for (int pt = 0; pt < 4; ++pt) {
        const int p = pt * 16 + (lane >> 4) * 4;
        *(float4*)&orow[p] = *(float4*)&acc[pt];
    }
}

extern "C" void kernel_launch(void* const* d_in, const int* in_sizes, int n_in,
                              void* d_out, int out_size, void* d_ws, size_t ws_size,
                              hipStream_t stream)
{
    const float* latent   = (const float*)d_in[0];
    const float* last_fm  = (const float*)d_in[1];
    const float* W_embed  = (const float*)d_in[2];
    const float* W_refine = (const float*)d_in[3];
    const int* bfs_order  = (const int*)d_in[4];
    const int* bfs_parent = (const int*)d_in[5];
    float* out = (float*)d_out;

    char* ws = (char*)d_ws;
    size_t off = 0;
    auto alloc = [&](size_t bytes) -> char* {
        char* p = ws + off;
        off = (off + bytes + 255) & ~(size_t)255;
        return p;
    };
    float* sRg  = (float*)alloc((size_t)BATCH * NPIX * 4);              // 256 KB
    float* sDg  = (float*)alloc((size_t)BATCH * NPIX * 4);              // 256 KB
    unsigned int* listKK = (unsigned int*)alloc((size_t)BATCH * LCAP * 4);
    float* listW = (float*)alloc((size_t)BATCH * LCAP * 4);
    int* loffg = (int*)alloc((size_t)BATCH * (NR + 1) * 4);
    unsigned int* tKPg = (unsigned int*)alloc((size_t)BATCH * LCAP * 4);
    float* tOMWg = (float*)alloc((size_t)BATCH * LCAP * 4);
    float* tRNg = (float*)alloc((size_t)BATCH * LCAP * 4);
    int* tcntg = (int*)alloc((size_t)BATCH * 4);
    float* scaleg = (float*)alloc((size_t)BATCH * NPIX * 4);            // 256 KB
    short* fixg = (short*)alloc((size_t)BATCH * NPIX * 2);              // 128 KB
    float* dltg = (float*)alloc((size_t)BATCH * LCAP * CCH * 4);        // 8.4 MB
    unsigned short* Wrg = (unsigned short*)alloc((size_t)CCH * CCH * 2);

    k_embedw<<<dim3(NPIX / EP, BATCH, 2), dim3(256), 0, stream>>>(last_fm, W_embed, sRg, sDg);
    k_prep<<<dim3(BATCH), dim3(1024), 0, stream>>>(bfs_order, bfs_parent, sRg, sDg,
        W_refine, Wrg, listKK, listW, loffg, tKPg, tOMWg, tRNg, tcntg, scaleg, fixg);
    k_sparse<<<dim3(BATCH * 32), dim3(256), 0, stream>>>(last_fm,
        listKK, listW, loffg, tKPg, tOMWg, tRNg, tcntg, dltg);
    k_refine<<<dim3(NPIX / RP, BATCH, 2), dim3(256), 0, stream>>>(last_fm, latent, scaleg,
        fixg, dltg, Wrg, out);
}

// Round 13
// 69.596 us; speedup vs baseline: 1.1254x; 1.1254x over previous
//
#include <hip/hip_runtime.h>
#include <hip/hip_bf16.h>

#define NPIX 8192
#define BATCH 8
#define CCH 128
#define CEMB 64
#define NR 13            // doubling rounds: covers ancestor distance < 8192
#define LCAP 2048        // entry-list / touched-list capacity per batch
#define STHR 69.0f       // s <= 69 <=> w = exp(-s) >= ~1e-30

typedef short bf16x8 __attribute__((ext_vector_type(8)));
typedef float f32x4 __attribute__((ext_vector_type(4)));

__device__ __forceinline__ unsigned short f2b(float f) {   // f32 -> bf16 RNE
    unsigned int u = __float_as_uint(f);
    u = (u + 0x7FFFu + ((u >> 16) & 1u)) >> 16;
    return (unsigned short)u;
}
__device__ __forceinline__ unsigned int cvtpk(float lo, float hi) {
    unsigned int r;
    asm("v_cvt_pk_bf16_f32 %0, %1, %2" : "=v"(r) : "v"(lo), "v"(hi));
    return r;
}

// ---------------------------------------------------------------------------
// Fused embed + edge-energy via MFMA (bf16, Delta-x formulation):
//   s_right[p] = || W_embed (x[p+1]-x[p]) ||^2
//   s_down [p] = || W_embed (x[p+128]-x[p]) ||^2
// (R10-proven form: combined directions, float4 staging, one latency round.)
// Block (0,0) additionally converts W_refine -> swizzled bf16 Wrg for
// k_refine (hidden inside this kernel; no extra launch).
// ---------------------------------------------------------------------------
#define EP 64
__global__ void __launch_bounds__(256) k_embedw(
    const float* __restrict__ last_fm,
    const float* __restrict__ W_embed,
    const float* __restrict__ W_refine,
    unsigned short* __restrict__ Wrg,    // [CCH*CCH] swizzled bf16 (out)
    float* __restrict__ sR,              // [B][NPIX]
    float* __restrict__ sD)              // [B][NPIX]
{
    __shared__ __align__(16) unsigned short Wh[CEMB * CCH];    // 16KB
    __shared__ __align__(16) unsigned short BR[16 * EP * 8];   // 16KB
    __shared__ __align__(16) unsigned short BD[16 * EP * 8];   // 16KB
    const int tid = threadIdx.x;
    const int b = blockIdx.y;
    const int pbase = blockIdx.x * EP;

    if (blockIdx.x == 0 && blockIdx.y == 0) {
        for (int i = tid; i < CCH * CCH; i += 256) {
            const int o = i >> 7, c = i & 127;
            Wrg[o * 128 + (((c >> 3) ^ (o & 15)) << 3) + (c & 7)] = f2b(W_refine[i]);
        }
    }
    for (int i = tid; i < CEMB * CCH; i += 256) {
        const int ce = i >> 7, c = i & 127;
        Wh[ce * 128 + (((c >> 3) ^ (ce & 15)) << 3) + (c & 7)] = f2b(W_embed[i]);
    }
    {
        const int chunk = tid >> 4, p4 = tid & 15;
        const int gp4 = pbase + p4 * 4;
        const bool hr = gp4 + 4 < NPIX;          // next float4's .x exists
        const bool hd = gp4 + 131 < NPIX;        // down float4 fully in range
        float4 a[8], d[8]; float xn[8];
#pragma unroll
        for (int j = 0; j < 8; ++j) {
            const float* src = last_fm + ((size_t)(b * CCH + chunk * 8 + j)) * NPIX;
            a[j] = *(const float4*)&src[gp4];
            xn[j] = hr ? src[gp4 + 4] : a[j].w;
            d[j] = hd ? *(const float4*)&src[gp4 + 128] : a[j];
        }
#pragma unroll
        for (int q = 0; q < 4; ++q) {
            const int p = p4 * 4 + q;
            const int row = p * 16 + (chunk ^ (p & 15));
            float r8[8], d8[8];
#pragma unroll
            for (int j = 0; j < 8; ++j) {
                const float aq = (&a[j].x)[q];
                r8[j] = ((q < 3) ? (&a[j].x)[q + 1] : xn[j]) - aq;
                d8[j] = (&d[j].x)[q] - aq;
            }
            uint4 ur, ud;
            ur.x = cvtpk(r8[0], r8[1]); ur.y = cvtpk(r8[2], r8[3]);
            ur.z = cvtpk(r8[4], r8[5]); ur.w = cvtpk(r8[6], r8[7]);
            ud.x = cvtpk(d8[0], d8[1]); ud.y = cvtpk(d8[2], d8[3]);
            ud.z = cvtpk(d8[4], d8[5]); ud.w = cvtpk(d8[6], d8[7]);
            *(uint4*)&BR[row * 8] = ur;
            *(uint4*)&BD[row * 8] = ud;
        }
    }
    __syncthreads();

    const int lane = tid & 63, wv = tid >> 6;
    f32x4 ar[4], ad[4];
#pragma unroll
    for (int i = 0; i < 4; ++i) {
        ar[i] = (f32x4){0.f, 0.f, 0.f, 0.f};
        ad[i] = (f32x4){0.f, 0.f, 0.f, 0.f};
    }
    const int pl = wv * 16 + (lane & 15);
#pragma unroll
    for (int ks = 0; ks < 4; ++ks) {
        const int chunk = ks * 4 + (lane >> 4);
        const int row = pl * 16 + (chunk ^ (pl & 15));
        const bf16x8 br = *(const bf16x8*)&BR[row * 8];
        const bf16x8 bd = *(const bf16x8*)&BD[row * 8];
#pragma unroll
        for (int ot = 0; ot < 4; ++ot) {
            const int ce = ot * 16 + (lane & 15);
            const bf16x8 aw = *(const bf16x8*)&Wh[ce * 128 + ((chunk ^ (ce & 15)) << 3)];
            ar[ot] = __builtin_amdgcn_mfma_f32_16x16x32_bf16(aw, br, ar[ot], 0, 0, 0);
            ad[ot] = __builtin_amdgcn_mfma_f32_16x16x32_bf16(aw, bd, ad[ot], 0, 0, 0);
        }
    }
    float pr = 0.f, pd = 0.f;
#pragma unroll
    for (int ot = 0; ot < 4; ++ot)
#pragma unroll
        for (int r = 0; r < 4; ++r) {
            pr += ar[ot][r] * ar[ot][r];
            pd += ad[ot][r] * ad[ot][r];
        }
    pr += __shfl_xor(pr, 16); pr += __shfl_xor(pr, 32);
    pd += __shfl_xor(pd, 16); pd += __shfl_xor(pd, 32);
    if (lane < 16) {
        const int p = pbase + wv * 16 + lane;
        sR[(size_t)b * NPIX + p] = pr;
        sD[(size_t)b * NPIX + p] = pd;
    }
}

// ---------------------------------------------------------------------------
// Wave-level exclusive scan over a 1024-thread block (3 barriers, not 10).
// ---------------------------------------------------------------------------
__device__ __forceinline__ unsigned int wave_scan_offset(
    unsigned int c, unsigned int* wtot, int tid, unsigned int* total)
{
    __syncthreads();                         // protect wtot reuse
    unsigned int x = c;
#pragma unroll
    for (int off = 1; off < 64; off <<= 1) {
        const unsigned int y = __shfl_up(x, off);
        if ((tid & 63) >= off) x += y;
    }
    if ((tid & 63) == 63) wtot[tid >> 6] = x;
    __syncthreads();
    if (tid < 16) {
        unsigned int t = wtot[tid];
#pragma unroll
        for (int off = 1; off < 16; off <<= 1) {
            const unsigned int y = __shfl_up(t, off);
            if (tid >= off) t += y;
        }
        wtot[tid] = t;
    }
    __syncthreads();
    const unsigned int waveOff = (tid >> 6) ? wtot[(tid >> 6) - 1] : 0u;
    *total = wtot[15];
    return waveOff + x - c;
}

// ---------------------------------------------------------------------------
// Prep (per batch, 1024 thr): w from s-arrays (edge identified by pixel-index
// delta +-1/+-128), thresholded -> compact doubling-entry lists, touched list,
// per-touched (1-w^2), 1/norm, per-pixel dense scale, per-pixel fixidx.
// ---------------------------------------------------------------------------
__global__ void __launch_bounds__(1024) k_prep(
    const int* __restrict__ bfs_order,
    const int* __restrict__ bfs_parent,
    const float* __restrict__ sR,
    const float* __restrict__ sD,
    unsigned int* __restrict__ listKK,   // [B][LCAP]
    float* __restrict__ listW,           // [B][LCAP]
    int* __restrict__ loffg,             // [B][NR+1]
    unsigned int* __restrict__ tKPg,     // [B][LCAP]
    float* __restrict__ tOMWg,           // [B][LCAP]
    float* __restrict__ tRNg,            // [B][LCAP]
    int* __restrict__ tcntg,             // [B]
    float* __restrict__ scaleg,          // [B][NPIX] pixel order
    short* __restrict__ fixidx)          // [B][NPIX] pixel order, -1 default
{
    __shared__ unsigned short anc[NPIX];            // 16KB (in-place doubled)
    __shared__ float Wc[NPIX];                      // 32KB (doubled; later normA)
    __shared__ float w0[NPIX];                      // 32KB persistent weights
    __shared__ unsigned short ordL[NPIX];           // 16KB bfs k -> pixel
    __shared__ unsigned short mk[NPIX];             // 16KB touched marks
    __shared__ unsigned int wtot[16];               // scan scratch
    __shared__ unsigned int eKK[LCAP];              // 8KB entry cache
    __shared__ float eW[LCAP];                      // 8KB
    __shared__ unsigned int tKPc[LCAP];             // 8KB touched cache
    __shared__ int loffL[NR + 1];
    __shared__ int sTot;

    const int b = blockIdx.x, tid = threadIdx.x;
    const int* par = bfs_parent + (size_t)b * NPIX;
    const int* ord = bfs_order + (size_t)b * NPIX;
    const size_t base = (size_t)b * NPIX;

    for (int k = tid; k < NPIX; k += 1024) {
        anc[k] = k ? (unsigned short)par[k] : 0;     // root self-loop
        ordL[k] = (unsigned short)ord[k];
        mk[k] = 0;
        scaleg[base + k] = 1.0f;                     // default dense scale
        fixidx[base + k] = -1;
    }
    if (tid == 0) loffL[0] = 0;
    __syncthreads();
    for (int k = tid; k < NPIX; k += 1024) {
        float w = 0.f;
        if (k) {
            const int u = ordL[k], v = ordL[anc[k]];
            const int d = u - v;
            float s;
            if (d == 1)        s = sR[base + v];
            else if (d == -1)  s = sR[base + u];
            else if (d == 128) s = sD[base + v];
            else               s = sD[base + u];
            w = (s <= STHR) ? __expf(-s) : 0.f;
        }
        Wc[k] = w; w0[k] = w;
    }
    __syncthreads();

    // ---- doubling rounds with compaction (early exit when a round is empty) ----
    int r = 0;
    for (; r < NR; ++r) {
        const int k0 = tid * 8;
        float wv8[8]; unsigned short av[8]; unsigned int c = 0;
#pragma unroll
        for (int j = 0; j < 8; ++j) { wv8[j] = Wc[k0 + j]; av[j] = anc[k0 + j]; c += (wv8[j] != 0.f); }
        unsigned int total;
        const unsigned int off0 = wave_scan_offset(c, wtot, tid, &total);
        int wpos = loffL[r] + (int)off0;
#pragma unroll
        for (int j = 0; j < 8; ++j) {
            if (wv8[j] != 0.f) {
                if (wpos < LCAP) {
                    const unsigned int kk = (unsigned)(k0 + j) | ((unsigned)av[j] << 16);
                    listKK[(size_t)b * LCAP + wpos] = kk;
                    listW[(size_t)b * LCAP + wpos] = wv8[j];
                    eKK[wpos] = kk; eW[wpos] = wv8[j];
                    mk[k0 + j] = 1; mk[av[j]] = 1;
                }
                ++wpos;
            }
        }
        __syncthreads();
        const int tot = min((int)total, LCAP - loffL[r]);
        if (tid == 0) loffL[r + 1] = loffL[r] + tot;
        __syncthreads();
        if (tot == 0) { ++r; break; }
        if (r + 1 < NR) {  // in-place doubling: read-phase -> barrier -> write-phase
            unsigned short a2[8]; float w2[8];
#pragma unroll
            for (int j = 0; j < 8; ++j) { const int a = av[j]; w2[j] = wv8[j] * Wc[a]; a2[j] = anc[a]; }
            __syncthreads();
#pragma unroll
            for (int j = 0; j < 8; ++j) { Wc[k0 + j] = w2[j]; anc[k0 + j] = a2[j]; }
            __syncthreads();
        }
    }
    if (tid == 0) for (int rr = r; rr < NR; ++rr) loffL[rr + 1] = loffL[r];
    __syncthreads();
    if (tid <= NR) loffg[b * (NR + 1) + tid] = loffL[tid];

    // ---- touched compaction (sorted by k) ----
    {
        const int k0 = tid * 8;
        unsigned short fl[8]; unsigned int c = 0;
#pragma unroll
        for (int j = 0; j < 8; ++j) { fl[j] = mk[k0 + j]; c += fl[j]; }
        unsigned int total;
        const unsigned int off0 = wave_scan_offset(c, wtot, tid, &total);
        int wpos = (int)off0;
#pragma unroll
        for (int j = 0; j < 8; ++j) {
            if (fl[j]) {
                if (wpos < LCAP) {
                    const unsigned int tp = (unsigned)(k0 + j) | ((unsigned)ordL[k0 + j] << 16);
                    tKPg[(size_t)b * LCAP + wpos] = tp; tKPc[wpos] = tp;
                }
                ++wpos;
            }
        }
        if (tid == 0) { sTot = min((int)total, LCAP); tcntg[b] = min((int)total, LCAP); }
        __syncthreads();
    }

    // ---- norm channel sparse simulation (ones vector) ----
    float* normA = Wc;                               // Wc dead, reuse as f32 array
    for (int k = tid; k < NPIX; k += 1024) normA[k] = 1.0f;
    __syncthreads();
    for (int rr = 0; rr < NR; ++rr) {                // UP (ascending chunks)
        const int e0 = loffL[rr], e1 = loffL[rr + 1];
        for (int bb = e0; bb < e1; bb += 1024) {
            const int e = bb + tid; const bool ok = e < e1;
            const unsigned int kk = ok ? eKK[e] : 0u;
            const float W = ok ? eW[e] : 0.f;
            const float a = normA[kk & 0xFFFFu];
            __syncthreads();
            if (W != 0.f) atomicAdd(&normA[kk >> 16], W * a);
            __syncthreads();
        }
    }
    for (int k = tid; k < NPIX; k += 1024) {         // alpha = (1-w^2) * A
        const float w = w0[k];
        normA[k] *= (1.f - w * w);
    }
    __syncthreads();
    for (int rr = 0; rr < NR; ++rr) {                // DOWN (descending chunks)
        const int e0 = loffL[rr], e1 = loffL[rr + 1];
        if (e1 <= e0) continue;
        const int cst = e0 + ((e1 - 1 - e0) / 1024) * 1024;
        for (int bb = cst; bb >= e0; bb -= 1024) {
            const int e = bb + tid; const bool ok = e < e1;
            const unsigned int kk = ok ? eKK[e] : 0u;
            const float W = ok ? eW[e] : 0.f;
            const float va = normA[kk >> 16];
            const float vs = normA[kk & 0xFFFFu];
            __syncthreads();
            if (ok) normA[kk & 0xFFFFu] = fmaf(W, va, vs);
            __syncthreads();
        }
    }
    // ---- per-touched outputs + scale/fixidx overwrite ----
    const int tc = sTot;
    for (int i = tid; i < tc; i += 1024) {
        const unsigned int tp = tKPc[i];
        const int k = (int)(tp & 0xFFFFu), pix = (int)(tp >> 16);
        const float w = w0[k];
        const float omw2 = 1.f - w * w;
        const float rn = 1.f / normA[k];
        tOMWg[(size_t)b * LCAP + i] = omw2;
        tRNg[(size_t)b * LCAP + i] = rn;
        scaleg[base + pix] = omw2 * rn;
        fixidx[base + pix] = (short)i;
    }
}

// ---------------------------------------------------------------------------
// Sparse corrections: per (batch, channel) wave, exact doubling sweeps on
// touched nodes in LDS; emits filt[c] = Y*rn per touched pixel.
// ---------------------------------------------------------------------------
__global__ void __launch_bounds__(256) k_sparse(
    const float* __restrict__ last_fm,
    const unsigned int* __restrict__ listKK,
    const float* __restrict__ listW,
    const int* __restrict__ loffg,
    const unsigned int* __restrict__ tKPg,
    const float* __restrict__ tOMWg,
    const float* __restrict__ tRNg,
    const int* __restrict__ tcntg,
    float* __restrict__ dltg)           // [B][LCAP][CCH] filt values
{
    __shared__ float As[4][NPIX];            // 128KB
    const int lane = threadIdx.x & 63;
    const int wv = threadIdx.x >> 6;
    const int b = blockIdx.x >> 5;
    const int c = (blockIdx.x & 31) * 4 + wv;
    float* A = As[wv];
    const int tc = tcntg[b];
    const unsigned int* tkp = tKPg + (size_t)b * LCAP;
    const float* tom = tOMWg + (size_t)b * LCAP;
    const float* trn = tRNg + (size_t)b * LCAP;
    const unsigned int* lkk = listKK + (size_t)b * LCAP;
    const float* lw = listW + (size_t)b * LCAP;
    const float* src = last_fm + ((size_t)(b * CCH + c)) * NPIX;
    int lo[NR + 1];
#pragma unroll
    for (int i = 0; i <= NR; ++i) lo[i] = loffg[b * (NR + 1) + i];

    for (int i = lane; i < tc; i += 64) {
        const unsigned int tp = tkp[i];
        A[tp & 0xFFFFu] = src[tp >> 16];
    }
    for (int r = 0; r < NR; ++r) {
        for (int e0 = lo[r]; e0 < lo[r + 1]; e0 += 64) {
            const int e = e0 + lane; const bool ok = e < lo[r + 1];
            const unsigned int kk = ok ? lkk[e] : 0u;
            const float W = ok ? lw[e] : 0.f;
            const float a = A[kk & 0xFFFFu];
            if (ok && W != 0.f) atomicAdd(&A[kk >> 16], W * a);
        }
    }
    for (int i = lane; i < tc; i += 64) A[tkp[i] & 0xFFFFu] *= tom[i];
    for (int r = 0; r < NR; ++r) {
        const int e0 = lo[r], e1 = lo[r + 1];
        if (e1 <= e0) continue;
        const int cst = e0 + ((e1 - 1 - e0) / 64) * 64;
        for (int bb = cst; bb >= e0; bb -= 64) {
            const int e = bb + lane; const bool ok = e < e1;
            const unsigned int kk = ok ? lkk[e] : 0u;
            const float W = ok ? lw[e] : 0.f;
            const float va = A[kk >> 16];
            const float vs = A[kk & 0xFFFFu];
            if (ok) A[kk & 0xFFFFu] = fmaf(W, va, vs);
        }
    }
    for (int i = lane; i < tc; i += 64) {
        const unsigned int tp = tkp[i];
        const int k = (int)(tp & 0xFFFFu);
        dltg[((size_t)b * LCAP + i) * CCH + c] = A[k] * trn[i];
    }
}

// ---------------------------------------------------------------------------
// Refine via MFMA, operand-swapped (D[p][o]), W fragments loaded DIRECTLY
// from global Wrg (32KB, L2-resident) into registers -> LDS = 16KB XB only.
// X = latent + scale*last_fm (untouched) or latent + filt (touched, exact).
// ---------------------------------------------------------------------------
#define RP 64
__global__ void __launch_bounds__(256, 4) k_refine(
    const float* __restrict__ last_fm,
    const float* __restrict__ latent,
    const float* __restrict__ scaleg,
    const short* __restrict__ fixidx,
    const float* __restrict__ dltg,
    const unsigned short* __restrict__ Wrg,
    float* __restrict__ out)
{
    __shared__ __align__(16) unsigned short XB[16 * RP * 8];   // 16KB
    const int tid = threadIdx.x;
    const int b = blockIdx.y;
    const int pbase = blockIdx.x * RP;
    const int lane = tid & 63, wv = tid >> 6;

    {
        const int chunk = tid >> 4, p4 = tid & 15;
        const int gp4 = pbase + p4 * 4;
        const float4 sc4 = *(const float4*)&scaleg[(size_t)b * NPIX + gp4];
        const short4 fi4 = *(const short4*)&fixidx[(size_t)b * NPIX + gp4];
        float4 l[8], x[8];
#pragma unroll
        for (int j = 0; j < 8; ++j) {
            const size_t rb = ((size_t)(b * CCH + chunk * 8 + j)) * NPIX + gp4;
            l[j] = *(const float4*)&latent[rb];
            x[j] = *(const float4*)&last_fm[rb];
        }
        const short fiq[4] = {fi4.x, fi4.y, fi4.z, fi4.w};
#pragma unroll
        for (int q = 0; q < 4; ++q) {
            const int p = p4 * 4 + q;
            const int row = p * 16 + (chunk ^ (p & 15));
            float v[8];
            if (fiq[q] >= 0) {
#pragma unroll
                for (int j = 0; j < 8; ++j)
                    v[j] = (&l[j].x)[q]
                         + dltg[((size_t)b * LCAP + fiq[q]) * CCH + chunk * 8 + j];
            } else {
#pragma unroll
                for (int j = 0; j < 8; ++j)
                    v[j] = fmaf((&sc4.x)[q], (&x[j].x)[q], (&l[j].x)[q]);
            }
            uint4 u;
            u.x = cvtpk(v[0], v[1]); u.y = cvtpk(v[2], v[3]);
            u.z = cvtpk(v[4], v[5]); u.w = cvtpk(v[6], v[7]);
            *(uint4*)&XB[row * 8] = u;
        }
    }
    // W fragments direct from global (independent of LDS; overlaps barrier)
    bf16x8 bw[2][4];
#pragma unroll
    for (int ot = 0; ot < 2; ++ot) {
        const int o = wv * 32 + ot * 16 + (lane & 15);
#pragma unroll
        for (int ks = 0; ks < 4; ++ks) {
            const int chunk = ks * 4 + (lane >> 4);
            bw[ot][ks] = *(const bf16x8*)&Wrg[o * 128 + ((chunk ^ (o & 15)) << 3)];
        }
    }
    __syncthreads();

    f32x4 acc[8];                        // [ot][pt]
#pragma unroll
    for (int i = 0; i < 8; ++i) acc[i] = (f32x4){0.f, 0.f, 0.f, 0.f};
#pragma unroll
    for (int ks = 0; ks < 4; ++ks) {
        const int chunk = ks * 4 + (lane >> 4);
        bf16x8 ax[4];
#pragma unroll
        for (int pt = 0; pt < 4; ++pt) {
            const int p = pt * 16 + (lane & 15);
            const int row = p * 16 + (chunk ^ (p & 15));
            ax[pt] = *(const bf16x8*)&XB[row * 8];
        }
#pragma unroll
        for (int ot = 0; ot < 2; ++ot)
#pragma unroll
            for (int pt = 0; pt < 4; ++pt)
                acc[ot * 4 + pt] = __builtin_amdgcn_mfma_f32_16x16x32_bf16(
                    ax[pt], bw[ot][ks], acc[ot * 4 + pt], 0, 0, 0);
    }
#pragma unroll
    for (int ot = 0; ot < 2; ++ot) {
        const int o = wv * 32 + ot * 16 + (lane & 15);
        float* orow = &out[((size_t)(b * CCH + o)) * NPIX + pbase];
#pragma unroll
        for (int pt = 0; pt < 4; ++pt) {
            const int p = pt * 16 + (lane >> 4) * 4;
            *(float4*)&orow[p] = *(float4*)&acc[ot * 4 + pt];
        }
    }
}

extern "C" void kernel_launch(void* const* d_in, const int* in_sizes, int n_in,
                              void* d_out, int out_size, void* d_ws, size_t ws_size,
                              hipStream_t stream)
{
    const float* latent   = (const float*)d_in[0];
    const float* last_fm  = (const float*)d_in[1];
    const float* W_embed  = (const float*)d_in[2];
    const float* W_refine = (const float*)d_in[3];
    const int* bfs_order  = (const int*)d_in[4];
    const int* bfs_parent = (const int*)d_in[5];
    float* out = (float*)d_out;

    char* ws = (char*)d_ws;
    size_t off = 0;
    auto alloc = [&](size_t bytes) -> char* {
        char* p = ws + off;
        off = (off + bytes + 255) & ~(size_t)255;
        return p;
    };
    float* sRg  = (float*)alloc((size_t)BATCH * NPIX * 4);              // 256 KB
    float* sDg  = (float*)alloc((size_t)BATCH * NPIX * 4);              // 256 KB
    unsigned int* listKK = (unsigned int*)alloc((size_t)BATCH * LCAP * 4);
    float* listW = (float*)alloc((size_t)BATCH * LCAP * 4);
    int* loffg = (int*)alloc((size_t)BATCH * (NR + 1) * 4);
    unsigned int* tKPg = (unsigned int*)alloc((size_t)BATCH * LCAP * 4);
    float* tOMWg = (float*)alloc((size_t)BATCH * LCAP * 4);
    float* tRNg = (float*)alloc((size_t)BATCH * LCAP * 4);
    int* tcntg = (int*)alloc((size_t)BATCH * 4);
    float* scaleg = (float*)alloc((size_t)BATCH * NPIX * 4);            // 256 KB
    short* fixg = (short*)alloc((size_t)BATCH * NPIX * 2);              // 128 KB
    float* dltg = (float*)alloc((size_t)BATCH * LCAP * CCH * 4);        // 8.4 MB
    unsigned short* Wrg = (unsigned short*)alloc((size_t)CCH * CCH * 2);

    k_embedw<<<dim3(NPIX / EP, BATCH), dim3(256), 0, stream>>>(last_fm, W_embed,
        W_refine, Wrg, sRg, sDg);
    k_prep<<<dim3(BATCH), dim3(1024), 0, stream>>>(bfs_order, bfs_parent, sRg, sDg,
        listKK, listW, loffg, tKPg, tOMWg, tRNg, tcntg, scaleg, fixg);
    k_sparse<<<dim3(BATCH * 32), dim3(256), 0, stream>>>(last_fm,
        listKK, listW, loffg, tKPg, tOMWg, tRNg, tcntg, dltg);
    k_refine<<<dim3(NPIX / RP, BATCH), dim3(256), 0, stream>>>(last_fm, latent, scaleg,
        fixg, dltg, Wrg, out);
}